// Round 1
// baseline (664.988 us; speedup 1.0000x reference)
//
#include <hip/hip_runtime.h>
#include <hip/hip_bf16.h>
#include <math.h>

// Problem constants (from reference): B=32, L=2048, D_Q=D_V=1024, UNITS=512
#define NB 32
#define LL 2048
#define DV 1024
#define NU 512
#define NM (NB * LL)  // 65536 GEMM rows

typedef __attribute__((ext_vector_type(8))) short short8;   // 8 bf16 = one MFMA A/B frag
typedef __attribute__((ext_vector_type(4))) float f32x4;    // MFMA C/D frag

#define GLL16(g, l)                                                            \
  __builtin_amdgcn_global_load_lds(                                            \
      (const __attribute__((address_space(1))) void*)(g),                      \
      (__attribute__((address_space(3))) void*)(l), 16, 0, 0)

// ---------------------------------------------------------------------------
// Prep 1: per-batch input_len -> log(1 + count(mask==0))
__global__ __launch_bounds__(256) void masksum_kernel(
    const float* __restrict__ mask, float* __restrict__ loglen) {
  int b = blockIdx.x, tid = threadIdx.x;
  int lane = tid & 63, wid = tid >> 6;
  float c = 0.f;
#pragma unroll
  for (int j = 0; j < 8; j++)
    c += (mask[(size_t)b * LL + j * 256 + tid] == 0.f) ? 1.f : 0.f;
#pragma unroll
  for (int o = 32; o >= 1; o >>= 1) c += __shfl_xor(c, o, 64);
  __shared__ float red[4];
  if (lane == 0) red[wid] = c;
  __syncthreads();
  if (tid == 0) loglen[b] = logf(1.f + red[0] + red[1] + red[2] + red[3]);
}

// ---------------------------------------------------------------------------
// Prep 2: pack Wv (K=1024 x N=512 fp32) -> bf16 tiles [ntile][ktile][n(128)][k(32)]
__global__ __launch_bounds__(256) void wvpack_kernel(
    const float* __restrict__ Wv, __hip_bfloat16* __restrict__ wvpk) {
  int idx = blockIdx.x * 256 + threadIdx.x;  // 524288 total
  int k_in = idx & 31;
  int n_in = (idx >> 5) & 127;
  int ktile = (idx >> 12) & 31;
  int ntile = idx >> 17;
  int k = ktile * 32 + k_in;
  int n = ntile * 128 + n_in;
  wvpk[idx] = __float2bfloat16(Wv[(size_t)k * NU + n]);
}

// ---------------------------------------------------------------------------
// Prep 3: h[b,u] = q@Wh + all biases + log(1+timestep)*Wp[0] + loglen[b]*Wp[2]
__global__ __launch_bounds__(512) void h_kernel(
    const float* __restrict__ q, const float* __restrict__ Wh,
    const float* __restrict__ bh, const float* __restrict__ bv,
    const float* __restrict__ bp, const float* __restrict__ bm,
    const float* __restrict__ Wp, const int* __restrict__ ts,
    const float* __restrict__ loglen, float* __restrict__ h) {
  int b = blockIdx.x;
  int u = threadIdx.x;  // 512
  float acc = 0.f;
#pragma unroll 8
  for (int k = 0; k < 1024; k++) acc += q[b * 1024 + k] * Wh[(size_t)k * NU + u];
  float lt = logf(1.0f + (float)ts[0]);
  h[b * NU + u] = acc + bh[u] + bv[u] + bp[u] + bm[u] + lt * Wp[u] +
                  loglen[b] * Wp[2 * NU + u];
}

// ---------------------------------------------------------------------------
// Main: S = values@Wv (bf16 MFMA), fused epilogue tanh(S+E)*vw reduced over u.
// grid (4 ntiles, 512 mtiles), 256 threads (4 waves, 2x2 of 64x64).
__global__ __launch_bounds__(256) void score_kernel(
    const float* __restrict__ values, const __hip_bfloat16* __restrict__ wvpk,
    const float* __restrict__ h, const float* __restrict__ Wp,
    const float* __restrict__ Wm, const float* __restrict__ vw,
    const float* __restrict__ prev, float* __restrict__ partial) {
  int ntile = blockIdx.x;  // 0..3
  int mtile = blockIdx.y;  // 0..511
  int tid = threadIdx.x;
  int lane = tid & 63, wid = tid >> 6;
  int wr = wid >> 1, wc = wid & 1;
  int col = lane & 15, quad = lane >> 4;
  int b = mtile >> 4;
  int l0 = (mtile & 15) << 7;
  int rowbase = mtile << 7;

  __shared__ __align__(16) __hip_bfloat16 As[128 * 32];  // [row][k] 8 KB
  __shared__ __align__(16) __hip_bfloat16 Bs[128 * 32];  // [n][k]   8 KB
  __shared__ float hL[128], wp1L[128], vwL[128], wmL[5][128], loglS[128];
  __shared__ float prevs[132], scoreAcc[128];

  if (tid < 128) {
    int u = ntile * 128 + tid;
    hL[tid] = h[b * NU + u];
    wp1L[tid] = Wp[NU + u];
    vwL[tid] = vw[u];
#pragma unroll
    for (int j = 0; j < 5; j++) wmL[j][tid] = Wm[j * NU + u];
    loglS[tid] = __logf(2.0f + (float)(l0 + tid));
    scoreAcc[tid] = 0.f;
  }
  if (tid < 132) {
    int li = l0 - 2 + tid;
    prevs[tid] = (li >= 0 && li < LL) ? prev[(size_t)b * LL + li] : 0.f;
  }

  f32x4 zero4 = {0.f, 0.f, 0.f, 0.f};
  f32x4 acc[4][4];
#pragma unroll
  for (int i = 0; i < 4; i++)
#pragma unroll
    for (int j = 0; j < 4; j++) acc[i][j] = zero4;

  int row = tid >> 1, hlf = tid & 1;
  const float* asrc = values + (size_t)(rowbase + row) * DV + hlf * 16;
  __hip_bfloat16* adst = &As[row * 32 + hlf * 16];
  const char* bbase = (const char*)(wvpk + (size_t)ntile * 32 * 4096);

  for (int kt = 0; kt < 32; ++kt) {
    // stage B (already bf16, packed contiguous per tile) via global_load_lds
    const char* bsrc = bbase + (size_t)kt * 8192;
    int boff = tid * 16;
    GLL16(bsrc + boff, (char*)Bs + boff);
    GLL16(bsrc + boff + 4096, (char*)Bs + boff + 4096);
    // stage A: fp32 global -> bf16 LDS (manual convert)
    const float4* a4 = (const float4*)(asrc + kt * 32);
    float4 f0 = a4[0], f1 = a4[1], f2 = a4[2], f3 = a4[3];
    union {
      __hip_bfloat162 h2[8];
      int4 q[2];
    } pk;
    pk.h2[0] = __float22bfloat162_rn(make_float2(f0.x, f0.y));
    pk.h2[1] = __float22bfloat162_rn(make_float2(f0.z, f0.w));
    pk.h2[2] = __float22bfloat162_rn(make_float2(f1.x, f1.y));
    pk.h2[3] = __float22bfloat162_rn(make_float2(f1.z, f1.w));
    pk.h2[4] = __float22bfloat162_rn(make_float2(f2.x, f2.y));
    pk.h2[5] = __float22bfloat162_rn(make_float2(f2.z, f2.w));
    pk.h2[6] = __float22bfloat162_rn(make_float2(f3.x, f3.y));
    pk.h2[7] = __float22bfloat162_rn(make_float2(f3.z, f3.w));
    ((int4*)adst)[0] = pk.q[0];
    ((int4*)adst)[1] = pk.q[1];
    __syncthreads();

    short8 aF[4], bF[4];
#pragma unroll
    for (int t = 0; t < 4; t++)
      aF[t] = *(const short8*)&As[(wr * 64 + t * 16 + col) * 32 + quad * 8];
#pragma unroll
    for (int t = 0; t < 4; t++)
      bF[t] = *(const short8*)&Bs[(wc * 64 + t * 16 + col) * 32 + quad * 8];
#pragma unroll
    for (int tr = 0; tr < 4; tr++)
#pragma unroll
      for (int tc = 0; tc < 4; tc++)
        acc[tr][tc] = __builtin_amdgcn_mfma_f32_16x16x32_bf16(
            aF[tr], bF[tc], acc[tr][tc], 0, 0, 0);
    __syncthreads();
  }

  // Epilogue: E = h + log(2+l)*Wp1 + markov; score partial = sum_u tanh(S+E)*vw
  int rb = wr * 64, ub = wc * 64;
#pragma unroll
  for (int tr = 0; tr < 4; tr++) {
    float ps[4] = {0.f, 0.f, 0.f, 0.f};
#pragma unroll
    for (int tc = 0; tc < 4; tc++) {
      int uc = ub + tc * 16 + col;
      float hh = hL[uc], wp1 = wp1L[uc], vv = vwL[uc];
      float m0 = wmL[0][uc], m1 = wmL[1][uc], m2 = wmL[2][uc],
            m3 = wmL[3][uc], m4 = wmL[4][uc];
      int r0 = rb + tr * 16 + quad * 4;
#pragma unroll
      for (int i = 0; i < 4; i++) {
        int r = r0 + i;
        float e = hh + loglS[r] * wp1 + prevs[r] * m0 + prevs[r + 1] * m1 +
                  prevs[r + 2] * m2 + prevs[r + 3] * m3 + prevs[r + 4] * m4;
        float s = acc[tr][tc][i] + e;
        ps[i] += tanhf(s) * vv;
      }
    }
#pragma unroll
    for (int i = 0; i < 4; i++) {
      float v = ps[i];
      v += __shfl_xor(v, 1, 64);
      v += __shfl_xor(v, 2, 64);
      v += __shfl_xor(v, 4, 64);
      v += __shfl_xor(v, 8, 64);
      if (col == 0) atomicAdd(&scoreAcc[rb + tr * 16 + quad * 4 + i], v);
    }
  }
  __syncthreads();
  if (tid < 128)
    partial[(size_t)ntile * NM + rowbase + tid] = scoreAcc[tid];
}

// ---------------------------------------------------------------------------
// Softmax over L per batch; writes attention weights. (vb cancels in softmax.)
__global__ __launch_bounds__(256) void softmax_kernel(
    const float* __restrict__ partial, const float* __restrict__ mask,
    float* __restrict__ aw) {
  int b = blockIdx.x, tid = threadIdx.x;
  int lane = tid & 63, wid = tid >> 6;
  __shared__ float redmax[4], redsum[4];
  float sc[8];
  float mx = -3.0e38f;
#pragma unroll
  for (int j = 0; j < 8; j++) {
    size_t base = (size_t)b * LL + j * 256 + tid;
    float s = partial[base] + partial[NM + base] + partial[2 * (size_t)NM + base] +
              partial[3 * (size_t)NM + base];
    s += mask[base] * -1.0e9f;
    sc[j] = s;
    mx = fmaxf(mx, s);
  }
#pragma unroll
  for (int o = 32; o >= 1; o >>= 1) mx = fmaxf(mx, __shfl_xor(mx, o, 64));
  if (lane == 0) redmax[wid] = mx;
  __syncthreads();
  mx = fmaxf(fmaxf(redmax[0], redmax[1]), fmaxf(redmax[2], redmax[3]));
  float sum = 0.f;
#pragma unroll
  for (int j = 0; j < 8; j++) {
    float e = __expf(sc[j] - mx);
    sc[j] = e;
    sum += e;
  }
#pragma unroll
  for (int o = 32; o >= 1; o >>= 1) sum += __shfl_xor(sum, o, 64);
  if (lane == 0) redsum[wid] = sum;
  __syncthreads();
  sum = redsum[0] + redsum[1] + redsum[2] + redsum[3];
  float inv = 1.0f / sum;
#pragma unroll
  for (int j = 0; j < 8; j++)
    aw[(size_t)b * LL + j * 256 + tid] = sc[j] * inv;
}

// ---------------------------------------------------------------------------
// Context: out[b,d] = sum_l aw[b,l]*values[b,l,d]. grid (32 b, 16 l-chunks).
__global__ __launch_bounds__(256) void ctx_kernel(
    const float* __restrict__ values, const float* __restrict__ aw,
    float* __restrict__ out) {
  int b = blockIdx.x, lq = blockIdx.y, tid = threadIdx.x;
  const float4* vrow =
      (const float4*)(values + ((size_t)b * LL + lq * 128) * DV) + tid;
  const float* awb = aw + (size_t)b * LL + lq * 128;
  float4 acc = make_float4(0.f, 0.f, 0.f, 0.f);
#pragma unroll 4
  for (int l = 0; l < 128; l++) {
    float w = awb[l];
    float4 v = vrow[(size_t)l * 256];
    acc.x += w * v.x;
    acc.y += w * v.y;
    acc.z += w * v.z;
    acc.w += w * v.w;
  }
  float* o = out + (size_t)b * DV + tid * 4;
  atomicAdd(o + 0, acc.x);
  atomicAdd(o + 1, acc.y);
  atomicAdd(o + 2, acc.z);
  atomicAdd(o + 3, acc.w);
}

// ---------------------------------------------------------------------------
extern "C" void kernel_launch(void* const* d_in, const int* in_sizes, int n_in,
                              void* d_out, int out_size, void* d_ws,
                              size_t ws_size, hipStream_t stream) {
  const float* query = (const float*)d_in[0];
  const float* values = (const float*)d_in[1];
  const float* mask = (const float*)d_in[2];
  const float* prev = (const float*)d_in[3];
  const int* ts = (const int*)d_in[4];
  const float* Wh = (const float*)d_in[5];
  const float* bh = (const float*)d_in[6];
  const float* Wv = (const float*)d_in[7];
  const float* bv = (const float*)d_in[8];
  const float* Wp = (const float*)d_in[9];
  const float* bp = (const float*)d_in[10];
  const float* Wm = (const float*)d_in[11];
  const float* bm = (const float*)d_in[12];
  const float* vw = (const float*)d_in[13];
  // d_in[14] = vb: shift-invariant under softmax, unused.

  float* out = (float*)d_out;           // [0,32768) ctx, [32768,98304) aw
  float* ws = (float*)d_ws;
  float* loglen = ws;                   // 32 floats
  float* h = ws + 1024;                 // 32*512 floats
  float* partial = ws + 32768;          // 4*65536 floats
  __hip_bfloat16* wvpk =
      (__hip_bfloat16*)((char*)d_ws + (size_t)294912 * 4);  // 1 MB bf16
  // total ws use ~2.2 MB

  float* aw = out + 32768;

  hipMemsetAsync(d_out, 0, 32768 * sizeof(float), stream);  // ctx accumulators
  masksum_kernel<<<NB, 256, 0, stream>>>(mask, loglen);
  wvpack_kernel<<<2048, 256, 0, stream>>>(Wv, wvpk);
  h_kernel<<<NB, 512, 0, stream>>>(query, Wh, bh, bv, bp, bm, Wp, ts, loglen, h);
  score_kernel<<<dim3(4, 512), 256, 0, stream>>>(values, wvpk, h, Wp, Wm, vw,
                                                 prev, partial);
  softmax_kernel<<<NB, 256, 0, stream>>>(partial, mask, aw);
  ctx_kernel<<<dim3(NB, 16), 256, 0, stream>>>(values, aw, out);
}

// Round 3
// 515.029 us; speedup vs baseline: 1.2912x; 1.2912x over previous
//
#include <hip/hip_runtime.h>
#include <hip/hip_bf16.h>
#include <math.h>

// B=32, L=2048, D_Q=D_V=1024, UNITS=512
#define NB 32
#define LL 2048
#define DV 1024
#define NU 512
#define NM (NB * LL)

typedef __attribute__((ext_vector_type(8))) short short8;
typedef __attribute__((ext_vector_type(4))) float f32x4;

#define GLL16(g, l)                                                            \
  __builtin_amdgcn_global_load_lds(                                            \
      (const __attribute__((address_space(1))) void*)(g),                      \
      (__attribute__((address_space(3))) void*)(l), 16, 0, 0)

__device__ __forceinline__ float fast_tanh(float x) {
  x = fminf(fmaxf(x, -15.f), 15.f);
  float e = __expf(2.f * x);
  return (e - 1.f) / (e + 1.f);
}

// ---------------------------------------------------------------------------
__global__ __launch_bounds__(256) void masksum_kernel(
    const float* __restrict__ mask, float* __restrict__ loglen) {
  int b = blockIdx.x, tid = threadIdx.x;
  int lane = tid & 63, wid = tid >> 6;
  float c = 0.f;
#pragma unroll
  for (int j = 0; j < 8; j++)
    c += (mask[(size_t)b * LL + j * 256 + tid] == 0.f) ? 1.f : 0.f;
#pragma unroll
  for (int o = 32; o >= 1; o >>= 1) c += __shfl_xor(c, o, 64);
  __shared__ float red[4];
  if (lane == 0) red[wid] = c;
  __syncthreads();
  if (tid == 0) loglen[b] = logf(1.f + red[0] + red[1] + red[2] + red[3]);
}

// ---------------------------------------------------------------------------
// Pack Wv -> bf16, layout [ntile(2)][kt(32)][chunk(1024) of 16B], with the
// XOR chunk swizzle baked in: chunk j = n*4+c holds k-quad q = c ^ ((n>>1)&3).
__global__ __launch_bounds__(256) void wvpack_kernel(
    const float* __restrict__ Wv, __hip_bfloat16* __restrict__ wvpk) {
  int idx = blockIdx.x * 256 + threadIdx.x;  // 65536 chunks
  int c = idx & 3;
  int n = (idx >> 2) & 255;
  int kt = (idx >> 10) & 31;
  int nt = idx >> 15;
  int q = c ^ ((n >> 1) & 3);
  int u = nt * 256 + n;
  int k0 = kt * 32 + q * 8;
  union {
    __hip_bfloat162 h2[4];
    int4 v;
  } pk;
#pragma unroll
  for (int e = 0; e < 4; e++) {
    float a = Wv[(size_t)(k0 + 2 * e) * NU + u];
    float b = Wv[(size_t)(k0 + 2 * e + 1) * NU + u];
    pk.h2[e] = __float22bfloat162_rn(make_float2(a, b));
  }
  ((int4*)wvpk)[idx] = pk.v;
}

// ---------------------------------------------------------------------------
// h[b,u] = q@Wh + biases + log(1+ts)*Wp0 + loglen*Wp2.  K-split for occupancy.
__global__ __launch_bounds__(512) void h_kernel(
    const float* __restrict__ q, const float* __restrict__ Wh,
    const float* __restrict__ bh, const float* __restrict__ bv,
    const float* __restrict__ bp, const float* __restrict__ bm,
    const float* __restrict__ Wp, const int* __restrict__ ts,
    const float* __restrict__ loglen, float* __restrict__ h) {
  int b = blockIdx.x, ks = blockIdx.y;
  int u = threadIdx.x;
  __shared__ float qs[128];
  if (u < 128) qs[u] = q[b * 1024 + ks * 128 + u];
  __syncthreads();
  float acc = 0.f;
#pragma unroll 8
  for (int k = 0; k < 128; k++)
    acc += qs[k] * Wh[(size_t)(ks * 128 + k) * NU + u];
  if (ks == 0) {
    float lt = logf(1.0f + (float)ts[0]);
    acc += bh[u] + bv[u] + bp[u] + bm[u] + lt * Wp[u] + loglen[b] * Wp[2 * NU + u];
  }
  atomicAdd(&h[b * NU + u], acc);
}

// ---------------------------------------------------------------------------
// Score: S = values@Wv (bf16 MFMA), epilogue tanh(S+E)*vw reduced over u.
// Grid: 1024 linear blocks; remapped so the ntile-pair of one mtile lands on
// the same XCD (lin and lin+8 have equal lin%8) -> 2nd values read hits L2.
// Block: 256 thr = 4 waves (2x2), wave tile 64 rows x 128 cols, acc[4][8].
__global__ __launch_bounds__(256, 2) void score_kernel(
    const float* __restrict__ values, const __hip_bfloat16* __restrict__ wvpk,
    const float* __restrict__ h, const float* __restrict__ Wp,
    const float* __restrict__ Wm, const float* __restrict__ vw,
    const float* __restrict__ prev, float* __restrict__ partial) {
  int lin = blockIdx.x;
  int group = lin >> 4, sub = lin & 15;
  int ntile = sub >> 3;                 // 0..1
  int mtile = group * 8 + (sub & 7);    // 0..511
  int tid = threadIdx.x;
  int lane = tid & 63, wid = tid >> 6;
  int wr = wid >> 1, wc = wid & 1;
  int col = lane & 15, quad = lane >> 4;
  int b = mtile >> 4;
  int l0 = (mtile & 15) << 7;
  int rowbase = mtile << 7;

  __shared__ __align__(16) char AsB[8192];    // 128 rows x 64B, xor-swizzled
  __shared__ __align__(16) char BsB[16384];   // 256 cols x 64B, xor-swizzled
  __shared__ float hL[256], wp1L[256], vwL[256], wmL[5][256];
  __shared__ float loglS[128], prevs[132], scoreAcc[128];

  {
    int u = ntile * 256 + tid;
    hL[tid] = h[b * NU + u];
    wp1L[tid] = Wp[NU + u];
    vwL[tid] = vw[u];
#pragma unroll
    for (int j = 0; j < 5; j++) wmL[j][tid] = Wm[j * NU + u];
  }
  if (tid < 128) {
    loglS[tid] = __logf(2.0f + (float)(l0 + tid));
    scoreAcc[tid] = 0.f;
  }
  if (tid < 132) {
    int li = l0 - 2 + tid;
    prevs[tid] = (li >= 0 && li < LL) ? prev[(size_t)b * LL + li] : 0.f;
  }

  f32x4 acc[4][8];
  f32x4 zero4 = {0.f, 0.f, 0.f, 0.f};
#pragma unroll
  for (int i = 0; i < 4; i++)
#pragma unroll
    for (int j = 0; j < 8; j++) acc[i][j] = zero4;

  int row = tid >> 1, h0 = tid & 1;
  const float* abase = values + (size_t)(rowbase + row) * DV + h0 * 16;
  int s_sw = (row >> 1) & 3;
  char* adst0 = AsB + row * 64 + (((h0 * 2) ^ s_sw) * 16);
  char* adst1 = AsB + row * 64 + (((h0 * 2 + 1) ^ s_sw) * 16);
  const char* bbase = (const char*)wvpk + (size_t)ntile * 32 * 16384;
  int boff = tid * 16;

  // 2-deep A register prefetch (4 float4 per thread per kt)
  float4 preA[2][4];
#pragma unroll
  for (int d = 0; d < 2; d++) {
    const float4* p = (const float4*)(abase + d * 32);
#pragma unroll
    for (int j = 0; j < 4; j++) preA[d][j] = p[j];
  }

#define KSTEP(KT, PBUF)                                                        \
  {                                                                            \
    __syncthreads(); /* LDS free from previous compute */                      \
    const char* bsrc = bbase + (size_t)(KT) * 16384;                           \
    GLL16(bsrc + boff, BsB + boff);                                            \
    GLL16(bsrc + boff + 4096, BsB + boff + 4096);                              \
    GLL16(bsrc + boff + 8192, BsB + boff + 8192);                              \
    GLL16(bsrc + boff + 12288, BsB + boff + 12288);                            \
    float4 f0 = preA[PBUF][0], f1 = preA[PBUF][1];                             \
    float4 f2 = preA[PBUF][2], f3 = preA[PBUF][3];                             \
    union {                                                                    \
      __hip_bfloat162 h2[8];                                                   \
      int4 qq[2];                                                              \
    } pk;                                                                      \
    pk.h2[0] = __float22bfloat162_rn(make_float2(f0.x, f0.y));                 \
    pk.h2[1] = __float22bfloat162_rn(make_float2(f0.z, f0.w));                 \
    pk.h2[2] = __float22bfloat162_rn(make_float2(f1.x, f1.y));                 \
    pk.h2[3] = __float22bfloat162_rn(make_float2(f1.z, f1.w));                 \
    pk.h2[4] = __float22bfloat162_rn(make_float2(f2.x, f2.y));                 \
    pk.h2[5] = __float22bfloat162_rn(make_float2(f2.z, f2.w));                 \
    pk.h2[6] = __float22bfloat162_rn(make_float2(f3.x, f3.y));                 \
    pk.h2[7] = __float22bfloat162_rn(make_float2(f3.z, f3.w));                 \
    *(int4*)adst0 = pk.qq[0];                                                  \
    *(int4*)adst1 = pk.qq[1];                                                  \
    __syncthreads(); /* publish; drains GLL(KT) + aged A(KT+1) */              \
    if ((KT) < 30) { /* reload issued post-barrier: ages a full compute */     \
      const float4* nx = (const float4*)(abase + ((KT) + 2) * 32);             \
      preA[PBUF][0] = nx[0];                                                   \
      preA[PBUF][1] = nx[1];                                                   \
      preA[PBUF][2] = nx[2];                                                   \
      preA[PBUF][3] = nx[3];                                                   \
    }                                                                          \
    short8 aF[4];                                                              \
    _Pragma("unroll") for (int t = 0; t < 4; t++) {                            \
      int m = wr * 64 + t * 16 + col;                                          \
      aF[t] = *(const short8*)(AsB + m * 64 + ((quad ^ ((m >> 1) & 3)) * 16)); \
    }                                                                          \
    _Pragma("unroll") for (int tc = 0; tc < 8; tc++) {                         \
      int n = wc * 128 + tc * 16 + col;                                        \
      short8 bF =                                                              \
          *(const short8*)(BsB + n * 64 + ((quad ^ ((n >> 1) & 3)) * 16));     \
      _Pragma("unroll") for (int tr = 0; tr < 4; tr++) acc[tr][tc] =           \
          __builtin_amdgcn_mfma_f32_16x16x32_bf16(aF[tr], bF, acc[tr][tc], 0,  \
                                                  0, 0);                       \
    }                                                                          \
  }

  for (int kto = 0; kto < 16; kto++) {
    KSTEP(2 * kto, 0);
    KSTEP(2 * kto + 1, 1);
  }
#undef KSTEP

  // Epilogue
  int rb = wr * 64;
#pragma unroll
  for (int tr = 0; tr < 4; tr++) {
    float ps[4] = {0.f, 0.f, 0.f, 0.f};
#pragma unroll
    for (int tc = 0; tc < 8; tc++) {
      int uc = wc * 128 + tc * 16 + col;
      float hh = hL[uc], wp1 = wp1L[uc], vv = vwL[uc];
      float m0 = wmL[0][uc], m1 = wmL[1][uc], m2 = wmL[2][uc],
            m3 = wmL[3][uc], m4 = wmL[4][uc];
      int r0 = rb + tr * 16 + quad * 4;
#pragma unroll
      for (int i = 0; i < 4; i++) {
        int r = r0 + i;
        float e = hh + loglS[r] * wp1 + prevs[r] * m0 + prevs[r + 1] * m1 +
                  prevs[r + 2] * m2 + prevs[r + 3] * m3 + prevs[r + 4] * m4;
        float sv = acc[tr][tc][i] + e;
        ps[i] += fast_tanh(sv) * vv;
      }
    }
#pragma unroll
    for (int i = 0; i < 4; i++) {
      float v = ps[i];
      v += __shfl_xor(v, 1, 64);
      v += __shfl_xor(v, 2, 64);
      v += __shfl_xor(v, 4, 64);
      v += __shfl_xor(v, 8, 64);
      if (col == 0) atomicAdd(&scoreAcc[rb + tr * 16 + quad * 4 + i], v);
    }
  }
  __syncthreads();
  if (tid < 128)
    partial[(size_t)ntile * NM + rowbase + tid] = scoreAcc[tid];
}

// ---------------------------------------------------------------------------
__global__ __launch_bounds__(256) void softmax_kernel(
    const float* __restrict__ partial, const float* __restrict__ mask,
    float* __restrict__ aw) {
  int b = blockIdx.x, tid = threadIdx.x;
  int lane = tid & 63, wid = tid >> 6;
  __shared__ float redmax[4], redsum[4];
  float sc[8];
  float mx = -3.0e38f;
#pragma unroll
  for (int j = 0; j < 8; j++) {
    size_t base = (size_t)b * LL + j * 256 + tid;
    float s = partial[base] + partial[(size_t)NM + base];
    s += mask[base] * -1.0e9f;
    sc[j] = s;
    mx = fmaxf(mx, s);
  }
#pragma unroll
  for (int o = 32; o >= 1; o >>= 1) mx = fmaxf(mx, __shfl_xor(mx, o, 64));
  if (lane == 0) redmax[wid] = mx;
  __syncthreads();
  mx = fmaxf(fmaxf(redmax[0], redmax[1]), fmaxf(redmax[2], redmax[3]));
  float sum = 0.f;
#pragma unroll
  for (int j = 0; j < 8; j++) {
    float e = __expf(sc[j] - mx);
    sc[j] = e;
    sum += e;
  }
#pragma unroll
  for (int o = 32; o >= 1; o >>= 1) sum += __shfl_xor(sum, o, 64);
  if (lane == 0) redsum[wid] = sum;
  __syncthreads();
  sum = redsum[0] + redsum[1] + redsum[2] + redsum[3];
  float inv = 1.0f / sum;
#pragma unroll
  for (int j = 0; j < 8; j++)
    aw[(size_t)b * LL + j * 256 + tid] = sc[j] * inv;
}

// ---------------------------------------------------------------------------
__global__ __launch_bounds__(256) void ctx_kernel(
    const float* __restrict__ values, const float* __restrict__ aw,
    float* __restrict__ out) {
  int b = blockIdx.x, lq = blockIdx.y, tid = threadIdx.x;
  const float4* vrow =
      (const float4*)(values + ((size_t)b * LL + lq * 64) * DV) + tid;
  const float* awb = aw + (size_t)b * LL + lq * 64;
  float4 acc = make_float4(0.f, 0.f, 0.f, 0.f);
#pragma unroll 8
  for (int l = 0; l < 64; l++) {
    float w = awb[l];
    float4 v = vrow[(size_t)l * 256];
    acc.x += w * v.x;
    acc.y += w * v.y;
    acc.z += w * v.z;
    acc.w += w * v.w;
  }
  float* o = out + (size_t)b * DV + tid * 4;
  atomicAdd(o + 0, acc.x);
  atomicAdd(o + 1, acc.y);
  atomicAdd(o + 2, acc.z);
  atomicAdd(o + 3, acc.w);
}

// ---------------------------------------------------------------------------
extern "C" void kernel_launch(void* const* d_in, const int* in_sizes, int n_in,
                              void* d_out, int out_size, void* d_ws,
                              size_t ws_size, hipStream_t stream) {
  const float* query = (const float*)d_in[0];
  const float* values = (const float*)d_in[1];
  const float* mask = (const float*)d_in[2];
  const float* prev = (const float*)d_in[3];
  const int* ts = (const int*)d_in[4];
  const float* Wh = (const float*)d_in[5];
  const float* bh = (const float*)d_in[6];
  const float* Wv = (const float*)d_in[7];
  const float* bv = (const float*)d_in[8];
  const float* Wp = (const float*)d_in[9];
  const float* bp = (const float*)d_in[10];
  const float* Wm = (const float*)d_in[11];
  const float* bm = (const float*)d_in[12];
  const float* vw = (const float*)d_in[13];
  // d_in[14] = vb: cancels under softmax.

  float* out = (float*)d_out;   // [0,32768) ctx, [32768,98304) aw
  float* ws = (float*)d_ws;
  float* loglen = ws;                    // 32 f
  float* h = ws + 1024;                  // 16384 f
  float* partial = ws + 32768;           // 2*65536 f
  __hip_bfloat16* wvpk =
      (__hip_bfloat16*)((char*)d_ws + (size_t)163840 * 4);  // 1 MB
  float* aw = out + 32768;

  hipMemsetAsync(d_out, 0, 32768 * sizeof(float), stream);          // ctx acc
  hipMemsetAsync((char*)d_ws + 4096, 0, 16384 * sizeof(float), stream);  // h
  masksum_kernel<<<NB, 256, 0, stream>>>(mask, loglen);
  wvpack_kernel<<<256, 256, 0, stream>>>(Wv, wvpk);
  h_kernel<<<dim3(NB, 8), 512, 0, stream>>>(query, Wh, bh, bv, bp, bm, Wp, ts,
                                            loglen, h);
  score_kernel<<<1024, 256, 0, stream>>>(values, wvpk, h, Wp, Wm, vw, prev,
                                         partial);
  softmax_kernel<<<NB, 256, 0, stream>>>(partial, mask, aw);
  ctx_kernel<<<dim3(NB, 32), 256, 0, stream>>>(values, aw, out);
}